// Round 7
// baseline (452.599 us; speedup 1.0000x reference)
//
#include <hip/hip_runtime.h>
#include <hip/hip_bf16.h>

#define N_NODES 100000
#define N_EDGES 3200000
#define IN_CH 128
#define HID 64
#define N_CLASSES 10

// bucketized CSR build
#define NB 391          // ceil(100000/256) buckets of 256 nodes
#define NPB 256
#define BCAP 10240      // mean 8192, sigma~90
#define CHUNK 8192

typedef unsigned short u16;
typedef unsigned int u32;

static __device__ __forceinline__ float u2f(u32 u) {
    union { u32 i; float f; } v; v.i = u; return v.f;
}
static __device__ __forceinline__ u16 f2bf(float f) {
    __hip_bfloat16 b = __float2bfloat16(f);   // RNE
    return *(u16*)&b;
}
static __device__ __forceinline__ u32 pack2(float lo, float hi) {
    return (u32)f2bf(lo) | ((u32)f2bf(hi) << 16);
}

// ---------------- CSR build: pass A — bucket partition (packed u32 stage) ----------------

__global__ void __launch_bounds__(1024) passA_k(
        const int* __restrict__ src, const int* __restrict__ dst,
        int* __restrict__ bcnt, u32* __restrict__ stage) {
    __shared__ int lh[NB];
    __shared__ int lb[NB];
    for (int i = threadIdx.x; i < NB; i += 1024) lh[i] = 0;
    __syncthreads();
    int e0 = blockIdx.x * CHUNK;
#pragma unroll
    for (int k = 0; k < CHUNK / 1024; ++k) {
        int e = e0 + k * 1024 + threadIdx.x;
        if (e < N_EDGES) atomicAdd(&lh[dst[e] >> 8], 1);
    }
    __syncthreads();
    for (int i = threadIdx.x; i < NB; i += 1024) {
        lb[i] = atomicAdd(&bcnt[i], lh[i]);
        lh[i] = 0;
    }
    __syncthreads();
#pragma unroll
    for (int k = 0; k < CHUNK / 1024; ++k) {
        int e = e0 + k * 1024 + threadIdx.x;
        if (e < N_EDGES) {
            int d = dst[e];
            int b = d >> 8;
            int p = lb[b] + atomicAdd(&lh[b], 1);
            if (p < BCAP) stage[(size_t)b * BCAP + p] = ((u32)src[e] << 8) | (u32)(d & 255);
        }
    }
}

// ---------------- bucket scan ----------------

__global__ void bscan_k(const int* __restrict__ bcnt, int* __restrict__ bbase,
                        int* __restrict__ off) {
    __shared__ int s[512];
    int tid = threadIdx.x;
    int v = (tid < NB) ? min(bcnt[tid], BCAP) : 0;
    s[tid] = v;
    __syncthreads();
    for (int o = 1; o < 512; o <<= 1) {
        int t = (tid >= o) ? s[tid - o] : 0;
        __syncthreads();
        s[tid] += t;
        __syncthreads();
    }
    if (tid < NB) bbase[tid] = s[tid] - v;
    if (tid == NB - 1) off[N_NODES] = s[tid];
}

// ---------------- pass B — per-bucket CSR in LDS, coalesced writeout ----------------

__global__ void __launch_bounds__(1024) passB_k(
        const int* __restrict__ bcnt, const int* __restrict__ bbase,
        const u32* __restrict__ stage, int* __restrict__ off,
        int* __restrict__ csr) {
    __shared__ int ldeg[NPB];
    __shared__ int loff[NPB + 1];
    __shared__ int lcur[NPB];
    __shared__ int img[BCAP];
    int b = blockIdx.x;
    int nb = min(bcnt[b], BCAP);
    int base = bbase[b];
    const u32* st = stage + (size_t)b * BCAP;
    int tid = threadIdx.x;
    if (tid < NPB) ldeg[tid] = 0;
    __syncthreads();
    for (int i = tid; i < nb; i += 1024) atomicAdd(&ldeg[st[i] & 255u], 1);
    __syncthreads();
    if (tid < NPB) lcur[tid] = ldeg[tid];
    __syncthreads();
    for (int o = 1; o < NPB; o <<= 1) {
        int t = (tid < NPB && tid >= o) ? lcur[tid - o] : 0;
        __syncthreads();
        if (tid < NPB) lcur[tid] += t;
        __syncthreads();
    }
    if (tid < NPB) loff[tid + 1] = lcur[tid];
    if (tid == 0) loff[0] = 0;
    __syncthreads();
    if (tid < NPB) {
        int gnode = (b << 8) + tid;
        if (gnode < N_NODES) off[gnode] = base + loff[tid];
        lcur[tid] = loff[tid];
    }
    __syncthreads();
    for (int i = tid; i < nb; i += 1024) {
        u32 pr = st[i];
        int p = atomicAdd(&lcur[pr & 255u], 1);
        img[p] = (int)(pr >> 8);
    }
    __syncthreads();
    for (int i = tid; i < nb; i += 1024) csr[base + i] = img[i];
}

// swizzled weight fill (generic C x 64): sW4[(c>>2)*256 + out*4 + (c&3)] = W[c*64+out]
static __device__ __forceinline__ void fill_swz(float* sW4, const float* __restrict__ W,
                                                int nelem, int tid, int nthr) {
    for (int i = tid; i < nelem; i += nthr) {
        int c = i >> 6, out = i & 63;
        sW4[((c >> 2) << 8) + (out << 2) + (c & 3)] = W[i];
    }
}

// ---------------- y = x @ W1a  (no bias), stored bf16 ----------------

__global__ void __launch_bounds__(512) lin1_k(
        const float* __restrict__ x, const float* __restrict__ W1,
        u16* __restrict__ yb) {
    __shared__ __align__(16) float sW4[IN_CH * 64];   // 32 KB swizzled
    __shared__ __align__(16) float srow[8][IN_CH];
    fill_swz(sW4, W1, IN_CH * 64, threadIdx.x, 512);
    __syncthreads();
    int wid = threadIdx.x >> 6, lane = threadIdx.x & 63;
    int gw = blockIdx.x * 8 + wid;
    const int NW = 1024 * 8;
    for (int n = gw; n < N_NODES; n += NW) {
        srow[wid][lane]      = x[(size_t)n * IN_CH + lane];
        srow[wid][64 + lane] = x[(size_t)n * IN_CH + 64 + lane];
        __builtin_amdgcn_wave_barrier();
        float acc = 0.f;
#pragma unroll
        for (int c4 = 0; c4 < IN_CH / 4; ++c4) {
            float4 w = *(const float4*)&sW4[(c4 << 8) + (lane << 2)];
            float4 r = *(const float4*)&srow[wid][c4 << 2];
            acc = fmaf(r.x, w.x, acc); acc = fmaf(r.y, w.y, acc);
            acc = fmaf(r.z, w.z, acc); acc = fmaf(r.w, w.w, acc);
        }
        __builtin_amdgcn_wave_barrier();
        yb[(size_t)n * 64 + lane] = f2bf(acc);
    }
}

// ---------------- pure gather: out[n] = tab[n] + sum_{s in csr[n]} tab[s]  (bf16 rows) ----
// No LDS, no epilogue: waves keep gather loads in flight continuously.
// lane l -> edge slot g=l>>3, channel octet c=l&7; one wave-load = 8 rows x 128 B.

__global__ void __launch_bounds__(512) gather_k(
        const u16* __restrict__ tab, const int* __restrict__ off,
        const int* __restrict__ csr, u16* __restrict__ outb) {
    int wid = threadIdx.x >> 6, lane = threadIdx.x & 63;
    int g = lane >> 3, c = lane & 7;
    int coff = c << 4;
    const char* tb = (const char*)tab;
    int gw = blockIdx.x * 8 + wid;
    const int NW = 1024 * 8;
    for (int n = gw; n < N_NODES; n += NW) {
        float a0, a1, a2, a3, a4, a5, a6, a7;
        {   // self term (only group 0 keeps it)
            uint4 dS = *(const uint4*)(tb + (size_t)n * 128 + coff);
            u32 sm = (g == 0) ? 0xffffffffu : 0u;
            dS.x &= sm; dS.y &= sm; dS.z &= sm; dS.w &= sm;
            a0 = u2f(dS.x << 16); a1 = u2f(dS.x & 0xffff0000u);
            a2 = u2f(dS.y << 16); a3 = u2f(dS.y & 0xffff0000u);
            a4 = u2f(dS.z << 16); a5 = u2f(dS.z & 0xffff0000u);
            a6 = u2f(dS.w << 16); a7 = u2f(dS.w & 0xffff0000u);
        }
        int e = off[n], e1 = off[n + 1];
        int nfull = (e1 - e) >> 3;
#pragma unroll 4
        for (int it = 0; it < nfull; ++it) {
            int s = csr[e + g];
            uint4 d = *(const uint4*)(tb + (size_t)s * 128 + coff);
            a0 += u2f(d.x << 16); a1 += u2f(d.x & 0xffff0000u);
            a2 += u2f(d.y << 16); a3 += u2f(d.y & 0xffff0000u);
            a4 += u2f(d.z << 16); a5 += u2f(d.z & 0xffff0000u);
            a6 += u2f(d.w << 16); a7 += u2f(d.w & 0xffff0000u);
            e += 8;
        }
        int rem = e1 - e;
        if (rem > 0) {
            int s = csr[e + min(g, rem - 1)];
            u32 m = (g < rem) ? 0xffffffffu : 0u;
            uint4 d = *(const uint4*)(tb + (size_t)s * 128 + coff);
            d.x &= m; d.y &= m; d.z &= m; d.w &= m;
            a0 += u2f(d.x << 16); a1 += u2f(d.x & 0xffff0000u);
            a2 += u2f(d.y << 16); a3 += u2f(d.y & 0xffff0000u);
            a4 += u2f(d.z << 16); a5 += u2f(d.z & 0xffff0000u);
            a6 += u2f(d.w << 16); a7 += u2f(d.w & 0xffff0000u);
        }
        // reduce across the 8 edge groups
        a0 += __shfl_xor(a0, 8);  a1 += __shfl_xor(a1, 8);  a2 += __shfl_xor(a2, 8);
        a3 += __shfl_xor(a3, 8);  a4 += __shfl_xor(a4, 8);  a5 += __shfl_xor(a5, 8);
        a6 += __shfl_xor(a6, 8);  a7 += __shfl_xor(a7, 8);
        a0 += __shfl_xor(a0, 16); a1 += __shfl_xor(a1, 16); a2 += __shfl_xor(a2, 16);
        a3 += __shfl_xor(a3, 16); a4 += __shfl_xor(a4, 16); a5 += __shfl_xor(a5, 16);
        a6 += __shfl_xor(a6, 16); a7 += __shfl_xor(a7, 16);
        a0 += __shfl_xor(a0, 32); a1 += __shfl_xor(a1, 32); a2 += __shfl_xor(a2, 32);
        a3 += __shfl_xor(a3, 32); a4 += __shfl_xor(a4, 32); a5 += __shfl_xor(a5, 32);
        a6 += __shfl_xor(a6, 32); a7 += __shfl_xor(a7, 32);
        if (g == 0) {
            uint4 pk = make_uint4(pack2(a0, a1), pack2(a2, a3), pack2(a4, a5), pack2(a6, a7));
            *(uint4*)((char*)outb + (size_t)n * 128 + coff) = pk;
        }
    }
}

// ---------------- layer A MLP (streaming): h1 = relu(relu(agg + b1a) @ W2a + b2a) ----------

__global__ void __launch_bounds__(512) mlpA_k(
        const u16* __restrict__ gab, const float* __restrict__ b1,
        const float* __restrict__ W2, const float* __restrict__ b2,
        u16* __restrict__ h1b) {
    __shared__ __align__(16) float sW4[64 * 64];
    __shared__ __align__(16) float su[8][64];
    fill_swz(sW4, W2, 64 * 64, threadIdx.x, 512);
    __syncthreads();
    int wid = threadIdx.x >> 6, lane = threadIdx.x & 63;
    int g = lane >> 3, c = lane & 7;
    float4 b1v0 = ((const float4*)b1)[c * 2];
    float4 b1v1 = ((const float4*)b1)[c * 2 + 1];
    float bb2 = b2[lane];
    int gw = blockIdx.x * 8 + wid;
    const int NW = 1024 * 8;
    for (int n = gw; n < N_NODES; n += NW) {
        if (g == 0) {
            uint4 d = *(const uint4*)((const char*)gab + (size_t)n * 128 + (c << 4));
            float4 u0 = make_float4(fmaxf(u2f(d.x << 16) + b1v0.x, 0.f),
                                    fmaxf(u2f(d.x & 0xffff0000u) + b1v0.y, 0.f),
                                    fmaxf(u2f(d.y << 16) + b1v0.z, 0.f),
                                    fmaxf(u2f(d.y & 0xffff0000u) + b1v0.w, 0.f));
            float4 u1 = make_float4(fmaxf(u2f(d.z << 16) + b1v1.x, 0.f),
                                    fmaxf(u2f(d.z & 0xffff0000u) + b1v1.y, 0.f),
                                    fmaxf(u2f(d.w << 16) + b1v1.z, 0.f),
                                    fmaxf(u2f(d.w & 0xffff0000u) + b1v1.w, 0.f));
            *(float4*)&su[wid][c << 3] = u0;
            *(float4*)&su[wid][(c << 3) + 4] = u1;
        }
        __builtin_amdgcn_wave_barrier();
        float o = bb2;
#pragma unroll
        for (int c4 = 0; c4 < 16; ++c4) {
            float4 w = *(const float4*)&sW4[(c4 << 8) + (lane << 2)];
            float4 v = *(const float4*)&su[wid][c4 << 2];
            o = fmaf(w.x, v.x, o); o = fmaf(w.y, v.y, o);
            o = fmaf(w.z, v.z, o); o = fmaf(w.w, v.w, o);
        }
        __builtin_amdgcn_wave_barrier();
        h1b[(size_t)n * 64 + lane] = f2bf(fmaxf(o, 0.f));   // inter-layer relu
    }
}

// ---------------- layer B MLP + classifier + log_softmax (streaming) ----------------

__global__ void __launch_bounds__(512) mlpBcls_k(
        const u16* __restrict__ gbb, const float* __restrict__ W1,
        const float* __restrict__ b1, const float* __restrict__ W2,
        const float* __restrict__ b2, const float* __restrict__ Wl,
        const float* __restrict__ bl, float* __restrict__ out) {
    __shared__ __align__(16) float sW14[64 * 64];
    __shared__ __align__(16) float sW24[64 * 64];
    __shared__ float sWl[64 * N_CLASSES];
    __shared__ float sbl[16];
    __shared__ __align__(16) float su1[8][64];
    __shared__ __align__(16) float su2[8][64];
    fill_swz(sW14, W1, 64 * 64, threadIdx.x, 512);
    fill_swz(sW24, W2, 64 * 64, threadIdx.x, 512);
    for (int i = threadIdx.x; i < 64 * N_CLASSES; i += 512) sWl[i] = Wl[i];
    if (threadIdx.x < N_CLASSES) sbl[threadIdx.x] = bl[threadIdx.x];
    __syncthreads();
    int wid = threadIdx.x >> 6, lane = threadIdx.x & 63;
    int g = lane >> 3, c = lane & 7;
    float bb1 = b1[lane], bb2 = b2[lane];
    int gw = blockIdx.x * 8 + wid;
    const int NW = 1024 * 8;
    for (int n = gw; n < N_NODES; n += NW) {
        if (g == 0) {
            uint4 d = *(const uint4*)((const char*)gbb + (size_t)n * 128 + (c << 4));
            *(float4*)&su1[wid][c << 3] =
                make_float4(u2f(d.x << 16), u2f(d.x & 0xffff0000u),
                            u2f(d.y << 16), u2f(d.y & 0xffff0000u));
            *(float4*)&su1[wid][(c << 3) + 4] =
                make_float4(u2f(d.z << 16), u2f(d.z & 0xffff0000u),
                            u2f(d.w << 16), u2f(d.w & 0xffff0000u));
        }
        __builtin_amdgcn_wave_barrier();
        float u = bb1;
#pragma unroll
        for (int c4 = 0; c4 < 16; ++c4) {
            float4 w = *(const float4*)&sW14[(c4 << 8) + (lane << 2)];
            float4 v = *(const float4*)&su1[wid][c4 << 2];
            u = fmaf(w.x, v.x, u); u = fmaf(w.y, v.y, u);
            u = fmaf(w.z, v.z, u); u = fmaf(w.w, v.w, u);
        }
        u = fmaxf(u, 0.f);
        __builtin_amdgcn_wave_barrier();
        su2[wid][lane] = u;
        __builtin_amdgcn_wave_barrier();
        float o = bb2;
#pragma unroll
        for (int c4 = 0; c4 < 16; ++c4) {
            float4 w = *(const float4*)&sW24[(c4 << 8) + (lane << 2)];
            float4 v = *(const float4*)&su2[wid][c4 << 2];
            o = fmaf(w.x, v.x, o); o = fmaf(w.y, v.y, o);
            o = fmaf(w.z, v.z, o); o = fmaf(w.w, v.w, o);
        }
        float h2 = fmaxf(o, 0.f);                     // outer relu
        __builtin_amdgcn_wave_barrier();
        su1[wid][lane] = h2;                          // reuse su1 as h2 row
        __builtin_amdgcn_wave_barrier();
        // classifier: lanes 0..9 each compute one logit
        float logit = -3.0e38f;
        if (lane < N_CLASSES) {
            logit = sbl[lane];
#pragma unroll 8
            for (int cc = 0; cc < 64; ++cc)
                logit = fmaf(su1[wid][cc], sWl[cc * N_CLASSES + lane], logit);
        }
        // log-softmax across lanes 0..9 (reduce within 16-lane group)
        float m = logit;
        m = fmaxf(m, __shfl_xor(m, 1, 16));
        m = fmaxf(m, __shfl_xor(m, 2, 16));
        m = fmaxf(m, __shfl_xor(m, 4, 16));
        m = fmaxf(m, __shfl_xor(m, 8, 16));
        float ex = (lane < N_CLASSES) ? __expf(logit - m) : 0.f;
        float s = ex;
        s += __shfl_xor(s, 1, 16);
        s += __shfl_xor(s, 2, 16);
        s += __shfl_xor(s, 4, 16);
        s += __shfl_xor(s, 8, 16);
        float ls = __logf(s);
        if (lane < N_CLASSES) out[(size_t)n * N_CLASSES + lane] = logit - m - ls;
    }
}

// ---------------- launch ----------------

extern "C" void kernel_launch(void* const* d_in, const int* in_sizes, int n_in,
                              void* d_out, int out_size, void* d_ws, size_t ws_size,
                              hipStream_t stream) {
    const float* x   = (const float*)d_in[0];
    const int*   ei  = (const int*)d_in[1];
    const int*   src = ei;
    const int*   dst = ei + N_EDGES;
    const float* W1a = (const float*)d_in[2];
    const float* b1a = (const float*)d_in[3];
    const float* W2a = (const float*)d_in[4];
    const float* b2a = (const float*)d_in[5];
    const float* W1b = (const float*)d_in[6];
    const float* b1b = (const float*)d_in[7];
    const float* W2b = (const float*)d_in[8];
    const float* b2b = (const float*)d_in[9];
    const float* Wl  = (const float*)d_in[10];
    const float* bl  = (const float*)d_in[11];
    float* out = (float*)d_out;

    char* ws = (char*)d_ws;
    size_t o = 0;
    auto alloc = [&](size_t bytes) -> void* {
        o = (o + 255) & ~(size_t)255;
        void* p = ws + o;
        o += bytes;
        return p;
    };
    int* bcnt  = (int*)alloc((size_t)NB * 4);
    int* bbase = (int*)alloc((size_t)NB * 4);
    int* off   = (int*)alloc((size_t)(N_NODES + 1) * 4);
    u32* stage = (u32*)alloc((size_t)NB * BCAP * 4);     // 16.0 MB (packed)
    int* csr   = (int*)alloc((size_t)N_EDGES * 4);       // 12.8 MB
    u16* yb    = (u16*)alloc((size_t)N_NODES * 64 * 2);  // 12.8 MB
    u16* ga    = (u16*)alloc((size_t)N_NODES * 64 * 2);  // aggregated y
    u16* h1b   = (u16*)alloc((size_t)N_NODES * 64 * 2);
    u16* gb    = (u16*)alloc((size_t)N_NODES * 64 * 2);  // aggregated h1

    hipMemsetAsync(bcnt, 0, (size_t)NB * 4, stream);

    const int nA = (N_EDGES + CHUNK - 1) / CHUNK;        // 391
    passA_k<<<nA, 1024, 0, stream>>>(src, dst, bcnt, stage);
    bscan_k<<<1, 512, 0, stream>>>(bcnt, bbase, off);
    passB_k<<<NB, 1024, 0, stream>>>(bcnt, bbase, stage, off, csr);

    lin1_k   <<<1024, 512, 0, stream>>>(x, W1a, yb);
    gather_k <<<1024, 512, 0, stream>>>(yb, off, csr, ga);
    mlpA_k   <<<1024, 512, 0, stream>>>(ga, b1a, W2a, b2a, h1b);
    gather_k <<<1024, 512, 0, stream>>>(h1b, off, csr, gb);
    mlpBcls_k<<<1024, 512, 0, stream>>>(gb, W1b, b1b, W2b, b2b, Wl, bl, out);
}

// Round 9
// 323.773 us; speedup vs baseline: 1.3979x; 1.3979x over previous
//
#include <hip/hip_runtime.h>
#include <hip/hip_bf16.h>

#define N_NODES 100000
#define N_EDGES 3200000
#define IN_CH 128
#define HID 64
#define N_CLASSES 10
#define NTILES 6250     // N_NODES / 16

// bucketized CSR build
#define NB 391          // ceil(100000/256) buckets of 256 nodes
#define NPB 256
#define BCAP 10240      // mean 8192, sigma~90
#define CHUNK 8192

typedef unsigned short u16;
typedef unsigned int u32;

typedef __attribute__((ext_vector_type(8))) short bf16x8;  // 8 bf16 = 4 VGPR
typedef __attribute__((ext_vector_type(4))) float f32x4;   // MFMA acc

static __device__ __forceinline__ float u2f(u32 u) {
    union { u32 i; float f; } v; v.i = u; return v.f;
}
static __device__ __forceinline__ u16 f2bf(float f) {
    __hip_bfloat16 b = __float2bfloat16(f);   // RNE
    return *(u16*)&b;
}
static __device__ __forceinline__ u32 pack2(float lo, float hi) {
    return (u32)f2bf(lo) | ((u32)f2bf(hi) << 16);
}

// ---------------- CSR build: pass A — bucket partition (packed u32 stage) ----------------

__global__ void __launch_bounds__(1024) passA_k(
        const int* __restrict__ src, const int* __restrict__ dst,
        int* __restrict__ bcnt, u32* __restrict__ stage) {
    __shared__ int lh[NB];
    __shared__ int lb[NB];
    for (int i = threadIdx.x; i < NB; i += 1024) lh[i] = 0;
    __syncthreads();
    int e0 = blockIdx.x * CHUNK;
#pragma unroll
    for (int k = 0; k < CHUNK / 1024; ++k) {
        int e = e0 + k * 1024 + threadIdx.x;
        if (e < N_EDGES) atomicAdd(&lh[dst[e] >> 8], 1);
    }
    __syncthreads();
    for (int i = threadIdx.x; i < NB; i += 1024) {
        lb[i] = atomicAdd(&bcnt[i], lh[i]);
        lh[i] = 0;
    }
    __syncthreads();
#pragma unroll
    for (int k = 0; k < CHUNK / 1024; ++k) {
        int e = e0 + k * 1024 + threadIdx.x;
        if (e < N_EDGES) {
            int d = dst[e];
            int b = d >> 8;
            int p = lb[b] + atomicAdd(&lh[b], 1);
            if (p < BCAP) stage[(size_t)b * BCAP + p] = ((u32)src[e] << 8) | (u32)(d & 255);
        }
    }
}

// ---------------- bucket scan ----------------

__global__ void bscan_k(const int* __restrict__ bcnt, int* __restrict__ bbase,
                        int* __restrict__ off) {
    __shared__ int s[512];
    int tid = threadIdx.x;
    int v = (tid < NB) ? min(bcnt[tid], BCAP) : 0;
    s[tid] = v;
    __syncthreads();
    for (int o = 1; o < 512; o <<= 1) {
        int t = (tid >= o) ? s[tid - o] : 0;
        __syncthreads();
        s[tid] += t;
        __syncthreads();
    }
    if (tid < NB) bbase[tid] = s[tid] - v;
    if (tid == NB - 1) off[N_NODES] = s[tid];
}

// ---------------- pass B — per-bucket CSR in LDS, coalesced writeout ----------------

__global__ void __launch_bounds__(1024) passB_k(
        const int* __restrict__ bcnt, const int* __restrict__ bbase,
        const u32* __restrict__ stage, int* __restrict__ off,
        int* __restrict__ csr) {
    __shared__ int ldeg[NPB];
    __shared__ int loff[NPB + 1];
    __shared__ int lcur[NPB];
    __shared__ int img[BCAP];
    int b = blockIdx.x;
    int nb = min(bcnt[b], BCAP);
    int base = bbase[b];
    const u32* st = stage + (size_t)b * BCAP;
    int tid = threadIdx.x;
    if (tid < NPB) ldeg[tid] = 0;
    __syncthreads();
    for (int i = tid; i < nb; i += 1024) atomicAdd(&ldeg[st[i] & 255u], 1);
    __syncthreads();
    if (tid < NPB) lcur[tid] = ldeg[tid];
    __syncthreads();
    for (int o = 1; o < NPB; o <<= 1) {
        int t = (tid < NPB && tid >= o) ? lcur[tid - o] : 0;
        __syncthreads();
        if (tid < NPB) lcur[tid] += t;
        __syncthreads();
    }
    if (tid < NPB) loff[tid + 1] = lcur[tid];
    if (tid == 0) loff[0] = 0;
    __syncthreads();
    if (tid < NPB) {
        int gnode = (b << 8) + tid;
        if (gnode < N_NODES) off[gnode] = base + loff[tid];
        lcur[tid] = loff[tid];
    }
    __syncthreads();
    for (int i = tid; i < nb; i += 1024) {
        u32 pr = st[i];
        int p = atomicAdd(&lcur[pr & 255u], 1);
        img[p] = (int)(pr >> 8);
    }
    __syncthreads();
    for (int i = tid; i < nb; i += 1024) csr[base + i] = img[i];
}

// ---------------- pure gather: out[n] = tab[n] + sum_{s in csr[n]} tab[s]  (bf16 rows) ----

__global__ void __launch_bounds__(512) gather_k(
        const u16* __restrict__ tab, const int* __restrict__ off,
        const int* __restrict__ csr, u16* __restrict__ outb) {
    int wid = threadIdx.x >> 6, lane = threadIdx.x & 63;
    int g = lane >> 3, c = lane & 7;
    int coff = c << 4;
    const char* tb = (const char*)tab;
    int gw = blockIdx.x * 8 + wid;
    const int NW = 1024 * 8;
    for (int n = gw; n < N_NODES; n += NW) {
        float a0, a1, a2, a3, a4, a5, a6, a7;
        {   // self term (only group 0 keeps it)
            uint4 dS = *(const uint4*)(tb + (size_t)n * 128 + coff);
            u32 sm = (g == 0) ? 0xffffffffu : 0u;
            dS.x &= sm; dS.y &= sm; dS.z &= sm; dS.w &= sm;
            a0 = u2f(dS.x << 16); a1 = u2f(dS.x & 0xffff0000u);
            a2 = u2f(dS.y << 16); a3 = u2f(dS.y & 0xffff0000u);
            a4 = u2f(dS.z << 16); a5 = u2f(dS.z & 0xffff0000u);
            a6 = u2f(dS.w << 16); a7 = u2f(dS.w & 0xffff0000u);
        }
        int e = off[n], e1 = off[n + 1];
        int nfull = (e1 - e) >> 3;
#pragma unroll 4
        for (int it = 0; it < nfull; ++it) {
            int s = csr[e + g];
            uint4 d = *(const uint4*)(tb + (size_t)s * 128 + coff);
            a0 += u2f(d.x << 16); a1 += u2f(d.x & 0xffff0000u);
            a2 += u2f(d.y << 16); a3 += u2f(d.y & 0xffff0000u);
            a4 += u2f(d.z << 16); a5 += u2f(d.z & 0xffff0000u);
            a6 += u2f(d.w << 16); a7 += u2f(d.w & 0xffff0000u);
            e += 8;
        }
        int rem = e1 - e;
        if (rem > 0) {
            int s = csr[e + min(g, rem - 1)];
            u32 m = (g < rem) ? 0xffffffffu : 0u;
            uint4 d = *(const uint4*)(tb + (size_t)s * 128 + coff);
            d.x &= m; d.y &= m; d.z &= m; d.w &= m;
            a0 += u2f(d.x << 16); a1 += u2f(d.x & 0xffff0000u);
            a2 += u2f(d.y << 16); a3 += u2f(d.y & 0xffff0000u);
            a4 += u2f(d.z << 16); a5 += u2f(d.z & 0xffff0000u);
            a6 += u2f(d.w << 16); a7 += u2f(d.w & 0xffff0000u);
        }
        a0 += __shfl_xor(a0, 8);  a1 += __shfl_xor(a1, 8);  a2 += __shfl_xor(a2, 8);
        a3 += __shfl_xor(a3, 8);  a4 += __shfl_xor(a4, 8);  a5 += __shfl_xor(a5, 8);
        a6 += __shfl_xor(a6, 8);  a7 += __shfl_xor(a7, 8);
        a0 += __shfl_xor(a0, 16); a1 += __shfl_xor(a1, 16); a2 += __shfl_xor(a2, 16);
        a3 += __shfl_xor(a3, 16); a4 += __shfl_xor(a4, 16); a5 += __shfl_xor(a5, 16);
        a6 += __shfl_xor(a6, 16); a7 += __shfl_xor(a7, 16);
        a0 += __shfl_xor(a0, 32); a1 += __shfl_xor(a1, 32); a2 += __shfl_xor(a2, 32);
        a3 += __shfl_xor(a3, 32); a4 += __shfl_xor(a4, 32); a5 += __shfl_xor(a5, 32);
        a6 += __shfl_xor(a6, 32); a7 += __shfl_xor(a7, 32);
        if (g == 0) {
            uint4 pk = make_uint4(pack2(a0, a1), pack2(a2, a3), pack2(a4, a5), pack2(a6, a7));
            *(uint4*)((char*)outb + (size_t)n * 128 + coff) = pk;
        }
    }
}

// ---------------- MFMA helpers ----------------
// A-frag: lane holds A[lane&15][8*(lane>>4)+j]; B-frag: lane holds B[8*(lane>>4)+j][lane&15]
// D: lane reg i -> D[4*(lane>>4)+i][lane&15]   [verified m89]

static __device__ __forceinline__ bf16x8 bfragW(const float* __restrict__ W, int ncols,
                                                int kk, int nt, int lane) {
    int k0 = kk * 32 + ((lane >> 4) << 3);
    int col = nt * 16 + (lane & 15);
    bf16x8 b;
#pragma unroll
    for (int j = 0; j < 8; ++j) b[j] = (short)f2bf(W[(size_t)(k0 + j) * ncols + col]);
    return b;
}

static __device__ __forceinline__ bf16x8 bfragWl(const float* __restrict__ Wl,
                                                 int kk, int lane) {
    int k0 = kk * 32 + ((lane >> 4) << 3);
    int col = lane & 15;
    bf16x8 b;
#pragma unroll
    for (int j = 0; j < 8; ++j)
        b[j] = (col < N_CLASSES) ? (short)f2bf(Wl[(size_t)(k0 + j) * N_CLASSES + col]) : (short)0;
    return b;
}

// read A-frag from staged [16][68] u16 tile (b64-aligned reads)
static __device__ __forceinline__ bf16x8 afragSt(const u16* __restrict__ stw,
                                                 int kk, int lane) {
    const u16* p = stw + (size_t)(lane & 15) * 68 + kk * 32 + ((lane >> 4) << 3);
    uint2 q0 = *(const uint2*)p;
    uint2 q1 = *(const uint2*)(p + 4);
    union { uint2 u[2]; bf16x8 v; } cv;
    cv.u[0] = q0; cv.u[1] = q1;
    return cv.v;
}

// ---------------- y = x @ W1a (no bias), MFMA, stored bf16 ----------------

__global__ void __launch_bounds__(512) lin1_k(
        const float* __restrict__ x, const float* __restrict__ W1,
        u16* __restrict__ yb) {
    __shared__ u16 st[8][16][68];
    int wid = threadIdx.x >> 6, lane = threadIdx.x & 63;
    bf16x8 B[4][4];
#pragma unroll
    for (int kk = 0; kk < 4; ++kk)
#pragma unroll
        for (int nt = 0; nt < 4; ++nt) B[kk][nt] = bfragW(W1, 64, kk, nt, lane);
    int gw = blockIdx.x * 8 + wid;
    const int NW = 782 * 8;
    for (int t = gw; t < NTILES; t += NW) {
        int n0 = t << 4;
        f32x4 acc0 = {0.f, 0.f, 0.f, 0.f}, acc1 = acc0, acc2 = acc0, acc3 = acc0;
#pragma unroll
        for (int kk = 0; kk < 4; ++kk) {
            const float* xr = x + (size_t)(n0 + (lane & 15)) * IN_CH + kk * 32 + ((lane >> 4) << 3);
            float4 f0 = *(const float4*)xr;
            float4 f1 = *(const float4*)(xr + 4);
            bf16x8 a;
            a[0] = (short)f2bf(f0.x); a[1] = (short)f2bf(f0.y);
            a[2] = (short)f2bf(f0.z); a[3] = (short)f2bf(f0.w);
            a[4] = (short)f2bf(f1.x); a[5] = (short)f2bf(f1.y);
            a[6] = (short)f2bf(f1.z); a[7] = (short)f2bf(f1.w);
            acc0 = __builtin_amdgcn_mfma_f32_16x16x32_bf16(a, B[kk][0], acc0, 0, 0, 0);
            acc1 = __builtin_amdgcn_mfma_f32_16x16x32_bf16(a, B[kk][1], acc1, 0, 0, 0);
            acc2 = __builtin_amdgcn_mfma_f32_16x16x32_bf16(a, B[kk][2], acc2, 0, 0, 0);
            acc3 = __builtin_amdgcn_mfma_f32_16x16x32_bf16(a, B[kk][3], acc3, 0, 0, 0);
        }
        int r0 = (lane >> 4) << 2, cl = lane & 15;
#pragma unroll
        for (int i = 0; i < 4; ++i) {
            st[wid][r0 + i][cl]      = f2bf(acc0[i]);
            st[wid][r0 + i][16 + cl] = f2bf(acc1[i]);
            st[wid][r0 + i][32 + cl] = f2bf(acc2[i]);
            st[wid][r0 + i][48 + cl] = f2bf(acc3[i]);
        }
        __builtin_amdgcn_wave_barrier();
        {
            int row = lane >> 2, seg = lane & 3;
            const u16* sp = &st[wid][row][seg * 16];
            uint2 q0 = *(const uint2*)sp;
            uint2 q1 = *(const uint2*)(sp + 4);
            uint2 q2 = *(const uint2*)(sp + 8);
            uint2 q3 = *(const uint2*)(sp + 12);
            char* op = (char*)yb + (size_t)(n0 + row) * 128 + seg * 32;
            *(uint4*)op = make_uint4(q0.x, q0.y, q1.x, q1.y);
            *(uint4*)(op + 16) = make_uint4(q2.x, q2.y, q3.x, q3.y);
        }
        __builtin_amdgcn_wave_barrier();
    }
}

// ---------------- layer A MLP (MFMA): h1 = relu(relu(ga+b1a) @ W2a + b2a) ----------------

__global__ void __launch_bounds__(512) mlpA_k(
        const u16* __restrict__ ga, const float* __restrict__ b1,
        const float* __restrict__ W2, const float* __restrict__ b2,
        u16* __restrict__ h1b) {
    __shared__ u16 st[8][16][68];
    int wid = threadIdx.x >> 6, lane = threadIdx.x & 63;
    bf16x8 B[2][4];
#pragma unroll
    for (int kk = 0; kk < 2; ++kk)
#pragma unroll
        for (int nt = 0; nt < 4; ++nt) B[kk][nt] = bfragW(W2, 64, kk, nt, lane);
    float b1s[2][8];
#pragma unroll
    for (int kk = 0; kk < 2; ++kk)
#pragma unroll
        for (int j = 0; j < 8; ++j) b1s[kk][j] = b1[kk * 32 + ((lane >> 4) << 3) + j];
    float b2s[4];
#pragma unroll
    for (int nt = 0; nt < 4; ++nt) b2s[nt] = b2[nt * 16 + (lane & 15)];
    int gw = blockIdx.x * 8 + wid;
    const int NW = 782 * 8;
    for (int t = gw; t < NTILES; t += NW) {
        int n0 = t << 4;
        f32x4 acc0 = {0.f, 0.f, 0.f, 0.f}, acc1 = acc0, acc2 = acc0, acc3 = acc0;
#pragma unroll
        for (int kk = 0; kk < 2; ++kk) {
            uint4 raw = *(const uint4*)((const char*)ga + (size_t)(n0 + (lane & 15)) * 128
                                        + kk * 64 + ((lane >> 4) << 4));
            bf16x8 a;
            u32 w0 = raw.x, w1 = raw.y, w2 = raw.z, w3 = raw.w;
            a[0] = (short)f2bf(fmaxf(u2f(w0 << 16) + b1s[kk][0], 0.f));
            a[1] = (short)f2bf(fmaxf(u2f(w0 & 0xffff0000u) + b1s[kk][1], 0.f));
            a[2] = (short)f2bf(fmaxf(u2f(w1 << 16) + b1s[kk][2], 0.f));
            a[3] = (short)f2bf(fmaxf(u2f(w1 & 0xffff0000u) + b1s[kk][3], 0.f));
            a[4] = (short)f2bf(fmaxf(u2f(w2 << 16) + b1s[kk][4], 0.f));
            a[5] = (short)f2bf(fmaxf(u2f(w2 & 0xffff0000u) + b1s[kk][5], 0.f));
            a[6] = (short)f2bf(fmaxf(u2f(w3 << 16) + b1s[kk][6], 0.f));
            a[7] = (short)f2bf(fmaxf(u2f(w3 & 0xffff0000u) + b1s[kk][7], 0.f));
            acc0 = __builtin_amdgcn_mfma_f32_16x16x32_bf16(a, B[kk][0], acc0, 0, 0, 0);
            acc1 = __builtin_amdgcn_mfma_f32_16x16x32_bf16(a, B[kk][1], acc1, 0, 0, 0);
            acc2 = __builtin_amdgcn_mfma_f32_16x16x32_bf16(a, B[kk][2], acc2, 0, 0, 0);
            acc3 = __builtin_amdgcn_mfma_f32_16x16x32_bf16(a, B[kk][3], acc3, 0, 0, 0);
        }
        int r0 = (lane >> 4) << 2, cl = lane & 15;
#pragma unroll
        for (int i = 0; i < 4; ++i) {
            st[wid][r0 + i][cl]      = f2bf(fmaxf(acc0[i] + b2s[0], 0.f));
            st[wid][r0 + i][16 + cl] = f2bf(fmaxf(acc1[i] + b2s[1], 0.f));
            st[wid][r0 + i][32 + cl] = f2bf(fmaxf(acc2[i] + b2s[2], 0.f));
            st[wid][r0 + i][48 + cl] = f2bf(fmaxf(acc3[i] + b2s[3], 0.f));
        }
        __builtin_amdgcn_wave_barrier();
        {
            int row = lane >> 2, seg = lane & 3;
            const u16* sp = &st[wid][row][seg * 16];
            uint2 q0 = *(const uint2*)sp;
            uint2 q1 = *(const uint2*)(sp + 4);
            uint2 q2 = *(const uint2*)(sp + 8);
            uint2 q3 = *(const uint2*)(sp + 12);
            char* op = (char*)h1b + (size_t)(n0 + row) * 128 + seg * 32;
            *(uint4*)op = make_uint4(q0.x, q0.y, q1.x, q1.y);
            *(uint4*)(op + 16) = make_uint4(q2.x, q2.y, q3.x, q3.y);
        }
        __builtin_amdgcn_wave_barrier();
    }
}

// ---------------- layer B MLP + classifier + log_softmax (MFMA) ----------------

__global__ void __launch_bounds__(512) mlpBcls_k(
        const u16* __restrict__ gb, const float* __restrict__ W1,
        const float* __restrict__ b1, const float* __restrict__ W2,
        const float* __restrict__ b2, const float* __restrict__ Wl,
        const float* __restrict__ bl, float* __restrict__ out) {
    __shared__ u16 st[8][16][68];
    int wid = threadIdx.x >> 6, lane = threadIdx.x & 63;
    bf16x8 B1[2][4], B2[2][4], B3[2];
#pragma unroll
    for (int kk = 0; kk < 2; ++kk) {
#pragma unroll
        for (int nt = 0; nt < 4; ++nt) {
            B1[kk][nt] = bfragW(W1, 64, kk, nt, lane);
            B2[kk][nt] = bfragW(W2, 64, kk, nt, lane);
        }
        B3[kk] = bfragWl(Wl, kk, lane);
    }
    int cl = lane & 15;
    float b1s[4], b2s[4];
#pragma unroll
    for (int nt = 0; nt < 4; ++nt) { b1s[nt] = b1[nt * 16 + cl]; b2s[nt] = b2[nt * 16 + cl]; }
    float bls = (cl < N_CLASSES) ? bl[cl] : -1.0e30f;
    int gw = blockIdx.x * 8 + wid;
    const int NW = 782 * 8;
    for (int t = gw; t < NTILES; t += NW) {
        int n0 = t << 4;
        int r0 = (lane >> 4) << 2;
        // GEMM1: u = relu(gb @ W1b + b1b)
        f32x4 acc0 = {0.f, 0.f, 0.f, 0.f}, acc1 = acc0, acc2 = acc0, acc3 = acc0;
#pragma unroll
        for (int kk = 0; kk < 2; ++kk) {
            bf16x8 a = *(const bf16x8*)((const char*)gb + (size_t)(n0 + cl) * 128
                                        + kk * 64 + ((lane >> 4) << 4));
            acc0 = __builtin_amdgcn_mfma_f32_16x16x32_bf16(a, B1[kk][0], acc0, 0, 0, 0);
            acc1 = __builtin_amdgcn_mfma_f32_16x16x32_bf16(a, B1[kk][1], acc1, 0, 0, 0);
            acc2 = __builtin_amdgcn_mfma_f32_16x16x32_bf16(a, B1[kk][2], acc2, 0, 0, 0);
            acc3 = __builtin_amdgcn_mfma_f32_16x16x32_bf16(a, B1[kk][3], acc3, 0, 0, 0);
        }
#pragma unroll
        for (int i = 0; i < 4; ++i) {
            st[wid][r0 + i][cl]      = f2bf(fmaxf(acc0[i] + b1s[0], 0.f));
            st[wid][r0 + i][16 + cl] = f2bf(fmaxf(acc1[i] + b1s[1], 0.f));
            st[wid][r0 + i][32 + cl] = f2bf(fmaxf(acc2[i] + b1s[2], 0.f));
            st[wid][r0 + i][48 + cl] = f2bf(fmaxf(acc3[i] + b1s[3], 0.f));
        }
        __builtin_amdgcn_wave_barrier();
        // GEMM2: h2 = relu(u @ W2b + b2b)
        f32x4 d0 = {0.f, 0.f, 0.f, 0.f}, d1 = d0, d2 = d0, d3 = d0;
#pragma unroll
        for (int kk = 0; kk < 2; ++kk) {
            bf16x8 a = afragSt(&st[wid][0][0], kk, lane);
            d0 = __builtin_amdgcn_mfma_f32_16x16x32_bf16(a, B2[kk][0], d0, 0, 0, 0);
            d1 = __builtin_amdgcn_mfma_f32_16x16x32_bf16(a, B2[kk][1], d1, 0, 0, 0);
            d2 = __builtin_amdgcn_mfma_f32_16x16x32_bf16(a, B2[kk][2], d2, 0, 0, 0);
            d3 = __builtin_amdgcn_mfma_f32_16x16x32_bf16(a, B2[kk][3], d3, 0, 0, 0);
        }
        __builtin_amdgcn_wave_barrier();
#pragma unroll
        for (int i = 0; i < 4; ++i) {
            st[wid][r0 + i][cl]      = f2bf(fmaxf(d0[i] + b2s[0], 0.f));
            st[wid][r0 + i][16 + cl] = f2bf(fmaxf(d1[i] + b2s[1], 0.f));
            st[wid][r0 + i][32 + cl] = f2bf(fmaxf(d2[i] + b2s[2], 0.f));
            st[wid][r0 + i][48 + cl] = f2bf(fmaxf(d3[i] + b2s[3], 0.f));
        }
        __builtin_amdgcn_wave_barrier();
        // classifier: logits = h2 @ Wl + bl  (cols 10..15 forced to -1e30 via bls)
        f32x4 lg = {0.f, 0.f, 0.f, 0.f};
#pragma unroll
        for (int kk = 0; kk < 2; ++kk) {
            bf16x8 a = afragSt(&st[wid][0][0], kk, lane);
            lg = __builtin_amdgcn_mfma_f32_16x16x32_bf16(a, B3[kk], lg, 0, 0, 0);
        }
        __builtin_amdgcn_wave_barrier();
#pragma unroll
        for (int i = 0; i < 4; ++i) {
            float logit = lg[i] + bls;
            float m = logit;
            m = fmaxf(m, __shfl_xor(m, 1, 16));
            m = fmaxf(m, __shfl_xor(m, 2, 16));
            m = fmaxf(m, __shfl_xor(m, 4, 16));
            m = fmaxf(m, __shfl_xor(m, 8, 16));
            float ex = __expf(logit - m);
            float s = ex;
            s += __shfl_xor(s, 1, 16);
            s += __shfl_xor(s, 2, 16);
            s += __shfl_xor(s, 4, 16);
            s += __shfl_xor(s, 8, 16);
            float ls = __logf(s);
            if (cl < N_CLASSES)
                out[(size_t)(n0 + r0 + i) * N_CLASSES + cl] = logit - m - ls;
        }
    }
}

// ---------------- launch ----------------

extern "C" void kernel_launch(void* const* d_in, const int* in_sizes, int n_in,
                              void* d_out, int out_size, void* d_ws, size_t ws_size,
                              hipStream_t stream) {
    const float* x   = (const float*)d_in[0];
    const int*   ei  = (const int*)d_in[1];
    const int*   src = ei;
    const int*   dst = ei + N_EDGES;
    const float* W1a = (const float*)d_in[2];
    const float* b1a = (const float*)d_in[3];
    const float* W2a = (const float*)d_in[4];
    const float* b2a = (const float*)d_in[5];
    const float* W1b = (const float*)d_in[6];
    const float* b1b = (const float*)d_in[7];
    const float* W2b = (const float*)d_in[8];
    const float* b2b = (const float*)d_in[9];
    const float* Wl  = (const float*)d_in[10];
    const float* bl  = (const float*)d_in[11];
    float* out = (float*)d_out;

    char* ws = (char*)d_ws;
    size_t o = 0;
    auto alloc = [&](size_t bytes) -> void* {
        o = (o + 255) & ~(size_t)255;
        void* p = ws + o;
        o += bytes;
        return p;
    };
    int* bcnt  = (int*)alloc((size_t)NB * 4);
    int* bbase = (int*)alloc((size_t)NB * 4);
    int* off   = (int*)alloc((size_t)(N_NODES + 1) * 4);
    u32* stage = (u32*)alloc((size_t)NB * BCAP * 4);     // 16.0 MB (packed)
    int* csr   = (int*)alloc((size_t)N_EDGES * 4);       // 12.8 MB
    u16* yb    = (u16*)alloc((size_t)N_NODES * 64 * 2);  // 12.8 MB
    u16* ga    = (u16*)alloc((size_t)N_NODES * 64 * 2);  // aggregated y
    u16* h1b   = (u16*)alloc((size_t)N_NODES * 64 * 2);
    u16* gb    = (u16*)alloc((size_t)N_NODES * 64 * 2);  // aggregated h1

    hipMemsetAsync(bcnt, 0, (size_t)NB * 4, stream);

    const int nA = (N_EDGES + CHUNK - 1) / CHUNK;        // 391
    passA_k<<<nA, 1024, 0, stream>>>(src, dst, bcnt, stage);
    bscan_k<<<1, 512, 0, stream>>>(bcnt, bbase, off);
    passB_k<<<NB, 1024, 0, stream>>>(bcnt, bbase, stage, off, csr);

    lin1_k   <<<782, 512, 0, stream>>>(x, W1a, yb);
    gather_k <<<1024, 512, 0, stream>>>(yb, off, csr, ga);
    mlpA_k   <<<782, 512, 0, stream>>>(ga, b1a, W2a, b2a, h1b);
    gather_k <<<1024, 512, 0, stream>>>(h1b, off, csr, gb);
    mlpBcls_k<<<782, 512, 0, stream>>>(gb, W1b, b1b, W2b, b2b, Wl, bl, out);
}